// Round 1
// baseline (714.034 us; speedup 1.0000x reference)
//
#include <hip/hip_runtime.h>
#include <math.h>

typedef _Float16 half8 __attribute__((ext_vector_type(8)));
typedef _Float16 half4v __attribute__((ext_vector_type(4)));
typedef float f32x4 __attribute__((ext_vector_type(4)));

__device__ __forceinline__ _Float16 f2h(float f) { return (_Float16)f; }

// Generic fused GEMM: C[M=1024, N] = concat(A segs, each [1024][1024]) @ W^T + bias
// W = [W0 (k < w0cols, row-stride w0stride) | W1 (k >= w0cols, row-stride w1stride)]
// 128x128 tile, 4 waves (2x2), 16x16x32 f16 MFMA, f32->f16 convert during LDS staging.
__global__ __launch_bounds__(256) void gemm_f16(
    const float* __restrict__ A0, const float* __restrict__ A1,
    const float* __restrict__ A2, const float* __restrict__ A3,
    const float* __restrict__ A4,
    const float* __restrict__ W0, int w0cols, int w0stride,
    const float* __restrict__ W1, int w1stride,
    const float* __restrict__ bias0, const float* __restrict__ bias1,
    float* __restrict__ C, int ldc, int K)
{
    __shared__ _Float16 As[128 * 40];  // padded stride 40 elems (80 B, 16B-aligned rows)
    __shared__ _Float16 Ws[128 * 40];
    const int tid  = threadIdx.x;
    const int lane = tid & 63;
    const int wid  = tid >> 6;
    const int wm   = wid >> 1, wn = wid & 1;
    const int m0   = blockIdx.y * 128;
    const int n0   = blockIdx.x * 128;
    const int srow = tid >> 3;         // 0..31
    const int scol = (tid & 7) << 2;   // 0,4,...,28
    const int fr   = lane & 15;
    const int kq   = lane >> 4;

    f32x4 acc[4][4] = {};

    for (int k0 = 0; k0 < K; k0 += 32) {
        const int seg = k0 >> 10;
        const float* ap = (seg == 0) ? A0 : (seg == 1) ? A1 : (seg == 2) ? A2
                        : (seg == 3) ? A3 : A4;
        ap += (size_t)m0 * 1024 + (k0 & 1023);
        const float* wp; int wstr;
        if (k0 < w0cols) { wp = W0 + k0;            wstr = w0stride; }
        else             { wp = W1 + (k0 - w0cols); wstr = w1stride; }
        wp += (size_t)n0 * wstr;
        #pragma unroll
        for (int p = 0; p < 4; ++p) {
            int r = p * 32 + srow;
            float4 va = *reinterpret_cast<const float4*>(ap + (size_t)r * 1024 + scol);
            half4v ha = { f2h(va.x), f2h(va.y), f2h(va.z), f2h(va.w) };
            *reinterpret_cast<half4v*>(&As[r * 40 + scol]) = ha;
            float4 vw = *reinterpret_cast<const float4*>(wp + (size_t)r * wstr + scol);
            half4v hw = { f2h(vw.x), f2h(vw.y), f2h(vw.z), f2h(vw.w) };
            *reinterpret_cast<half4v*>(&Ws[r * 40 + scol]) = hw;
        }
        __syncthreads();
        half8 a[4], b[4];
        #pragma unroll
        for (int i = 0; i < 4; ++i) {
            a[i] = *reinterpret_cast<const half8*>(&As[(wm * 64 + i * 16 + fr) * 40 + kq * 8]);
            b[i] = *reinterpret_cast<const half8*>(&Ws[(wn * 64 + i * 16 + fr) * 40 + kq * 8]);
        }
        #pragma unroll
        for (int i = 0; i < 4; ++i)
            #pragma unroll
            for (int j = 0; j < 4; ++j)
                acc[i][j] = __builtin_amdgcn_mfma_f32_16x16x32_f16(a[i], b[j], acc[i][j], 0, 0, 0);
        __syncthreads();
    }
    // C/D layout (verified m89/m91): col = lane&15, row = (lane>>4)*4 + reg
    #pragma unroll
    for (int j = 0; j < 4; ++j) {
        int ncol = n0 + wn * 64 + j * 16 + fr;
        float bsum = bias0 ? bias0[ncol] : 0.f;
        if (bias1) bsum += bias1[ncol];
        #pragma unroll
        for (int i = 0; i < 4; ++i) {
            int rowb = m0 + wm * 64 + i * 16 + kq * 4;
            #pragma unroll
            for (int r = 0; r < 4; ++r)
                C[(size_t)(rowb + r) * ldc + ncol] = acc[i][j][r] + bsum;
        }
    }
}

// Elementwise LSTM cell from precomputed gates [B,4096] (i,f,g,o) + c_prev [B,R].
__global__ __launch_bounds__(256) void lstm_elem(
    const float* __restrict__ gates, const float* __restrict__ c_prev,
    float* __restrict__ h_ws, float* __restrict__ h_out,
    float* __restrict__ h_out2, float* __restrict__ c_out)
{
    int idx = blockIdx.x * blockDim.x + threadIdx.x;  // [0, 1M)
    int b = idx >> 10, r = idx & 1023;
    const float* g = gates + (size_t)b * 4096;
    float gi = g[r], gf = g[1024 + r], gg = g[2048 + r], go = g[3072 + r];
    float si = 1.f / (1.f + __expf(-gi));
    float sf = 1.f / (1.f + __expf(-gf));
    float so = 1.f / (1.f + __expf(-go));
    float c2 = sf * c_prev[idx] + si * tanhf(gg);
    float h2 = so * tanhf(c2);
    if (h_ws)   h_ws[idx]   = h2;
    h_out[idx] = h2;
    if (h_out2) h_out2[idx] = h2;
    c_out[idx] = c2;
}

// One block per batch row: scores -> softmax*mask/renorm -> weighted feature sum.
__global__ __launch_bounds__(256) void attend(
    const float* __restrict__ feats,   // [B,L,1024]
    const float* __restrict__ pfeats,  // [B,L,512]
    const float* __restrict__ mask,    // [B,L]
    const float* __restrict__ atth,    // [B,512]  (h @ Wq^T + bq, precomputed)
    const float* __restrict__ wa,      // [512]
    const float* __restrict__ ba,      // [1]
    float* __restrict__ out,           // [B,1024]
    int L)
{
    __shared__ float q[512];
    __shared__ float sc[64];
    __shared__ float wgt[64];
    const int tid = threadIdx.x;
    const int b = blockIdx.x;
    const int lane = tid & 63, wid = tid >> 6;
    for (int i = tid; i < 512; i += 256) q[i] = atth[(size_t)b * 512 + i];
    __syncthreads();
    for (int l = wid; l < L; l += 4) {
        const float* pf = pfeats + ((size_t)b * L + l) * 512;
        float s = 0.f;
        #pragma unroll
        for (int h0 = 0; h0 < 512; h0 += 64) {
            int h = h0 + lane;
            s += tanhf(pf[h] + q[h]) * wa[h];
        }
        #pragma unroll
        for (int off = 32; off >= 1; off >>= 1) s += __shfl_xor(s, off);
        if (lane == 0) sc[l] = s + ba[0];
    }
    __syncthreads();
    if (tid < 64) {
        float v = (tid < L) ? sc[tid] : -1e30f;
        float m = v;
        #pragma unroll
        for (int off = 32; off >= 1; off >>= 1) m = fmaxf(m, __shfl_xor(m, off));
        float e = (tid < L) ? __expf(v - m) : 0.f;
        float sum = e;
        #pragma unroll
        for (int off = 32; off >= 1; off >>= 1) sum += __shfl_xor(sum, off);
        float w = e / sum;
        float wm = (tid < L) ? w * mask[(size_t)b * L + tid] : 0.f;
        float s2 = wm;
        #pragma unroll
        for (int off = 32; off >= 1; off >>= 1) s2 += __shfl_xor(s2, off);
        wgt[tid] = wm / (s2 + 1e-8f);
    }
    __syncthreads();
    const int d0 = tid * 4;
    float ax = 0.f, ay = 0.f, az = 0.f, aw = 0.f;
    for (int l = 0; l < L; ++l) {
        float w = wgt[l];
        const float4 v = *reinterpret_cast<const float4*>(feats + ((size_t)b * L + l) * 1024 + d0);
        ax += w * v.x; ay += w * v.y; az += w * v.z; aw += w * v.w;
    }
    float4 o; o.x = ax; o.y = ay; o.z = az; o.w = aw;
    *reinterpret_cast<float4*>(out + (size_t)b * 1024 + d0) = o;
}

extern "C" void kernel_launch(void* const* d_in, const int* in_sizes, int n_in,
                              void* d_out, int out_size, void* d_ws, size_t ws_size,
                              hipStream_t stream)
{
    const size_t BR = 1024ull * 1024ull;
    const float* xt         = (const float*)d_in[0];
    const float* fc         = (const float*)d_in[1];
    const float* state_h    = (const float*)d_in[2];
    const float* state_c    = (const float*)d_in[3];
    const float* attr_feats = (const float*)d_in[4];
    const float* obj_feats  = (const float*)d_in[5];
    const float* rela_feats = (const float*)d_in[6];
    const float* p_attr     = (const float*)d_in[7];
    const float* p_obj      = (const float*)d_in[8];
    const float* p_rela     = (const float*)d_in[9];
    const float* attr_masks = (const float*)d_in[10];
    const float* att_masks  = (const float*)d_in[11];
    const float* rela_masks = (const float*)d_in[12];
    const float* att_Wih    = (const float*)d_in[13];
    const float* att_Whh    = (const float*)d_in[14];
    const float* att_bih    = (const float*)d_in[15];
    const float* att_bhh    = (const float*)d_in[16];
    const float* lang_Wih   = (const float*)d_in[17];
    const float* lang_Whh   = (const float*)d_in[18];
    const float* lang_bih   = (const float*)d_in[19];
    const float* lang_bhh   = (const float*)d_in[20];
    const float* attr_Wq    = (const float*)d_in[21];
    const float* attr_bq    = (const float*)d_in[22];
    const float* attr_wa    = (const float*)d_in[23];
    const float* attr_ba    = (const float*)d_in[24];
    const float* obj_Wq     = (const float*)d_in[25];
    const float* obj_bq     = (const float*)d_in[26];
    const float* obj_wa     = (const float*)d_in[27];
    const float* obj_ba     = (const float*)d_in[28];
    const float* rela_Wq    = (const float*)d_in[29];
    const float* rela_bq    = (const float*)d_in[30];
    const float* rela_wa    = (const float*)d_in[31];
    const float* rela_ba    = (const float*)d_in[32];

    float* out = (float*)d_out;
    float* ws  = (float*)d_ws;
    float* gates  = ws;                          // 1024*4096 = 4M floats
    float* h_att  = ws + 4 * BR;                 // 1M
    float* a_attr = ws + 5 * BR;                 // 1M
    float* a_obj  = ws + 6 * BR;                 // 1M
    float* a_rela = ws + 7 * BR;                 // 1M
    float* q_attr = ws + 8 * BR;                 // 512K
    float* q_obj  = ws + 8 * BR + 512 * 1024;    // 512K
    float* q_rela = ws + 9 * BR;                 // 512K

    dim3 blk(256);

    // 1) att-LSTM gates: A = [h1 | fc | xt | h0] (K=4096), W = [att_Wih | att_Whh]
    gemm_f16<<<dim3(32, 8), blk, 0, stream>>>(
        state_h + BR, fc, xt, state_h, state_h,
        att_Wih, 3072, 3072, att_Whh, 1024,
        att_bih, att_bhh, gates, 4096, 4096);
    // 2) att-LSTM elementwise: h_att (ws + out[h0 slot]), c_att (out[c0 slot])
    lstm_elem<<<dim3(4096), blk, 0, stream>>>(
        gates, state_c, h_att, out + BR, nullptr, out + 3 * BR);
    // 3) attention queries: q_p = h_att @ Wq^T + bq   (K=1024, N=512 each)
    gemm_f16<<<dim3(4, 8), blk, 0, stream>>>(
        h_att, h_att, h_att, h_att, h_att,
        attr_Wq, 1024, 1024, attr_Wq, 1024, attr_bq, nullptr, q_attr, 512, 1024);
    gemm_f16<<<dim3(4, 8), blk, 0, stream>>>(
        h_att, h_att, h_att, h_att, h_att,
        obj_Wq, 1024, 1024, obj_Wq, 1024, obj_bq, nullptr, q_obj, 512, 1024);
    gemm_f16<<<dim3(4, 8), blk, 0, stream>>>(
        h_att, h_att, h_att, h_att, h_att,
        rela_Wq, 1024, 1024, rela_Wq, 1024, rela_bq, nullptr, q_rela, 512, 1024);
    // 4) attend (scores -> softmax*mask/renorm -> weighted sum)
    attend<<<dim3(1024), blk, 0, stream>>>(
        attr_feats, p_attr, attr_masks, q_attr, attr_wa, attr_ba, a_attr, 16);
    attend<<<dim3(1024), blk, 0, stream>>>(
        obj_feats, p_obj, att_masks, q_obj, obj_wa, obj_ba, a_obj, 36);
    attend<<<dim3(1024), blk, 0, stream>>>(
        rela_feats, p_rela, rela_masks, q_rela, rela_wa, rela_ba, a_rela, 64);
    // 5) lang-LSTM gates: A = [h_att | a_attr | a_obj | a_rela | h1] (K=5120)
    gemm_f16<<<dim3(32, 8), blk, 0, stream>>>(
        h_att, a_attr, a_obj, a_rela, state_h + BR,
        lang_Wih, 4096, 4096, lang_Whh, 1024,
        lang_bih, lang_bhh, gates, 4096, 5120);
    // 6) lang-LSTM elementwise: output + h_lang + c_lang
    lstm_elem<<<dim3(4096), blk, 0, stream>>>(
        gates, state_c + BR, nullptr, out, out + 2 * BR, out + 4 * BR);
}

// Round 2
// 447.666 us; speedup vs baseline: 1.5950x; 1.5950x over previous
//
#include <hip/hip_runtime.h>
#include <math.h>

typedef _Float16 half8  __attribute__((ext_vector_type(8)));
typedef _Float16 half4v __attribute__((ext_vector_type(4)));
typedef float    f32x4  __attribute__((ext_vector_type(4)));

__device__ __forceinline__ _Float16 f2h(float f) { return (_Float16)f; }

// C_part[z][M=1024][ldc] (f16) = A[:, z*kHalf:(z+1)*kHalf] @ W[:, z*kHalf:(z+1)*kHalf]^T
// A = concat of 1024-wide f32 segments A0..A4; W = [W0 | W1] split along k at w0cols.
// 128x128 tile, BK=64, f16 LDS double-buffered + XOR swizzle, 4 waves (2x2).
__global__ __launch_bounds__(256, 2) void gemm_hf(
    const float* __restrict__ A0, const float* __restrict__ A1,
    const float* __restrict__ A2, const float* __restrict__ A3,
    const float* __restrict__ A4,
    const float* __restrict__ W0, int w0cols, int w0stride,
    const float* __restrict__ W1, int w1stride,
    _Float16* __restrict__ Cpart, int ldc, int kHalf)
{
    __shared__ _Float16 smA[2][128 * 64];
    __shared__ _Float16 smW[2][128 * 64];
    const int tid  = threadIdx.x;
    const int lane = tid & 63;
    const int wid  = tid >> 6;
    const int wm   = wid >> 1, wn = wid & 1;
    const int m0   = blockIdx.y * 128;
    const int n0   = blockIdx.x * 128;
    const int kb   = blockIdx.z * kHalf;
    const int nt   = kHalf >> 6;

    const int srow0  = tid >> 4;          // 0..15 (row within 16-row stripe)
    const int sc4    = (tid & 15) << 2;   // source col (elems), 0..60
    const int schunk = (tid & 15) >> 1;   // 16B chunk 0..7
    const int ssub   = (tid & 15) & 1;    // half-chunk
    const int swzci  = ((schunk ^ (srow0 & 7)) << 3) + (ssub << 2); // halves
    const int fr = lane & 15;
    const int kq = lane >> 4;

    f32x4 acc[4][4] = {};
    float4 va[8], vw[8];

#define LOADA(K0) { \
    int seg = (K0) >> 10; \
    const float* ap = (seg == 0) ? A0 : (seg == 1) ? A1 : (seg == 2) ? A2 \
                    : (seg == 3) ? A3 : A4; \
    ap += (size_t)m0 * 1024 + ((K0) & 1023) + sc4; \
    _Pragma("unroll") \
    for (int p = 0; p < 8; ++p) \
        va[p] = *reinterpret_cast<const float4*>(ap + (size_t)(srow0 + p * 16) * 1024); }

#define LOADW(K0) { \
    const float* wp; int wstr; \
    if ((K0) < w0cols) { wp = W0 + (K0);          wstr = w0stride; } \
    else               { wp = W1 + (K0) - w0cols; wstr = w1stride; } \
    wp += (size_t)n0 * wstr + sc4; \
    _Pragma("unroll") \
    for (int p = 0; p < 8; ++p) \
        vw[p] = *reinterpret_cast<const float4*>(wp + (size_t)(srow0 + p * 16) * wstr); }

#define WRITEA(BUF) { \
    _Float16* dstA = smA[(BUF)]; \
    _Pragma("unroll") \
    for (int p = 0; p < 8; ++p) { \
        half4v h = { f2h(va[p].x), f2h(va[p].y), f2h(va[p].z), f2h(va[p].w) }; \
        *reinterpret_cast<half4v*>(&dstA[(srow0 + p * 16) * 64 + swzci]) = h; } }

#define WRITEW(BUF) { \
    _Float16* dstW = smW[(BUF)]; \
    _Pragma("unroll") \
    for (int p = 0; p < 8; ++p) { \
        half4v h = { f2h(vw[p].x), f2h(vw[p].y), f2h(vw[p].z), f2h(vw[p].w) }; \
        *reinterpret_cast<half4v*>(&dstW[(srow0 + p * 16) * 64 + swzci]) = h; } }

#define DOMFMA(BUF, KS) { \
    half8 af[4], bf[4]; \
    _Pragma("unroll") \
    for (int i = 0; i < 4; ++i) { \
        int ar = wm * 64 + i * 16 + fr; \
        int br = wn * 64 + i * 16 + fr; \
        int ch = ((((KS) * 4 + kq) ^ (fr & 7)) << 3); \
        af[i] = *reinterpret_cast<const half8*>(&smA[(BUF)][ar * 64 + ch]); \
        bf[i] = *reinterpret_cast<const half8*>(&smW[(BUF)][br * 64 + ch]); \
    } \
    _Pragma("unroll") \
    for (int i = 0; i < 4; ++i) \
        _Pragma("unroll") \
        for (int j = 0; j < 4; ++j) \
            acc[i][j] = __builtin_amdgcn_mfma_f32_16x16x32_f16(af[i], bf[j], acc[i][j], 0, 0, 0); }

    // prologue: fill buffer 0
    LOADA(kb); WRITEA(0);
    LOADW(kb); WRITEW(0);
    __syncthreads();
    int cur = 0;
    for (int it = 0; it < nt - 1; ++it) {
        const int kn = kb + (it + 1) * 64;
        LOADA(kn);          // next-tile A loads in flight
        DOMFMA(cur, 0);     // compute hides load latency
        WRITEA(cur ^ 1);
        LOADW(kn);
        DOMFMA(cur, 1);
        WRITEW(cur ^ 1);
        __syncthreads();
        cur ^= 1;
    }
    DOMFMA(cur, 0);
    DOMFMA(cur, 1);

    _Float16* cp = Cpart + (size_t)blockIdx.z * 1024ull * (size_t)ldc;
    #pragma unroll
    for (int j = 0; j < 4; ++j) {
        int nc = n0 + wn * 64 + j * 16 + fr;
        #pragma unroll
        for (int i = 0; i < 4; ++i) {
            int rb = m0 + wm * 64 + i * 16 + kq * 4;
            #pragma unroll
            for (int r = 0; r < 4; ++r)
                cp[(size_t)(rb + r) * ldc + nc] = (_Float16)acc[i][j][r];
        }
    }
#undef LOADA
#undef LOADW
#undef WRITEA
#undef WRITEW
#undef DOMFMA
}

// LSTM elementwise from two f16 gate partials + biases.
__global__ __launch_bounds__(256) void lstm2(
    const _Float16* __restrict__ g0, const _Float16* __restrict__ g1,
    const float* __restrict__ bih, const float* __restrict__ bhh,
    const float* __restrict__ c_prev,
    float* __restrict__ h_out, float* __restrict__ h_out2,
    float* __restrict__ c_out)
{
    int idx = blockIdx.x * 256 + threadIdx.x;  // [0, 1M)
    int b = idx >> 10, r = idx & 1023;
    size_t base = (size_t)b * 4096;
    float gi = (float)g0[base + r]        + (float)g1[base + r]        + bih[r]        + bhh[r];
    float gf = (float)g0[base + 1024 + r] + (float)g1[base + 1024 + r] + bih[1024 + r] + bhh[1024 + r];
    float gg = (float)g0[base + 2048 + r] + (float)g1[base + 2048 + r] + bih[2048 + r] + bhh[2048 + r];
    float go = (float)g0[base + 3072 + r] + (float)g1[base + 3072 + r] + bih[3072 + r] + bhh[3072 + r];
    float si = 1.f / (1.f + __expf(-gi));
    float sf = 1.f / (1.f + __expf(-gf));
    float so = 1.f / (1.f + __expf(-go));
    float c2 = sf * c_prev[idx] + si * tanhf(gg);
    float h2 = so * tanhf(c2);
    h_out[idx] = h2;
    if (h_out2) h_out2[idx] = h2;
    c_out[idx] = c2;
}

// One block per batch row: scores -> softmax*mask/renorm -> weighted feature sum.
__global__ __launch_bounds__(256) void attend2(
    const float* __restrict__ feats,   // [B,L,1024]
    const float* __restrict__ pfeats,  // [B,L,512]
    const float* __restrict__ mask,    // [B,L]
    const _Float16* __restrict__ q0,   // [B,512] partial
    const _Float16* __restrict__ q1,   // [B,512] partial
    const float* __restrict__ bq,      // [512]
    const float* __restrict__ wa,      // [512]
    const float* __restrict__ ba,      // [1]
    float* __restrict__ outa,          // [B,1024]
    int L)
{
    __shared__ float q[512];
    __shared__ float sc[64];
    __shared__ float wgt[64];
    const int tid = threadIdx.x;
    const int b = blockIdx.x;
    const int lane = tid & 63, wid = tid >> 6;
    for (int i = tid; i < 512; i += 256)
        q[i] = (float)q0[(size_t)b * 512 + i] + (float)q1[(size_t)b * 512 + i] + bq[i];
    __syncthreads();
    for (int l = wid; l < L; l += 4) {
        const float* pf = pfeats + ((size_t)b * L + l) * 512;
        float s = 0.f;
        #pragma unroll
        for (int h0 = 0; h0 < 512; h0 += 64) {
            int h = h0 + lane;
            s += tanhf(pf[h] + q[h]) * wa[h];
        }
        #pragma unroll
        for (int off = 32; off >= 1; off >>= 1) s += __shfl_xor(s, off);
        if (lane == 0) sc[l] = s + ba[0];
    }
    __syncthreads();
    if (tid < 64) {
        float v = (tid < L) ? sc[tid] : -1e30f;
        float m = v;
        #pragma unroll
        for (int off = 32; off >= 1; off >>= 1) m = fmaxf(m, __shfl_xor(m, off));
        float e = (tid < L) ? __expf(v - m) : 0.f;
        float sum = e;
        #pragma unroll
        for (int off = 32; off >= 1; off >>= 1) sum += __shfl_xor(sum, off);
        float w = e / sum;
        float wm = (tid < L) ? w * mask[(size_t)b * L + tid] : 0.f;
        float s2 = wm;
        #pragma unroll
        for (int off = 32; off >= 1; off >>= 1) s2 += __shfl_xor(s2, off);
        wgt[tid] = wm / (s2 + 1e-8f);
    }
    __syncthreads();
    const int d0 = tid * 4;
    float ax = 0.f, ay = 0.f, az = 0.f, aw = 0.f;
    for (int l = 0; l < L; ++l) {
        float w = wgt[l];
        const float4 v = *reinterpret_cast<const float4*>(feats + ((size_t)b * L + l) * 1024 + d0);
        ax += w * v.x; ay += w * v.y; az += w * v.z; aw += w * v.w;
    }
    float4 o; o.x = ax; o.y = ay; o.z = az; o.w = aw;
    *reinterpret_cast<float4*>(outa + (size_t)b * 1024 + d0) = o;
}

extern "C" void kernel_launch(void* const* d_in, const int* in_sizes, int n_in,
                              void* d_out, int out_size, void* d_ws, size_t ws_size,
                              hipStream_t stream)
{
    const size_t BR = 1024ull * 1024ull;
    const float* xt         = (const float*)d_in[0];
    const float* fc         = (const float*)d_in[1];
    const float* state_h    = (const float*)d_in[2];
    const float* state_c    = (const float*)d_in[3];
    const float* attr_feats = (const float*)d_in[4];
    const float* obj_feats  = (const float*)d_in[5];
    const float* rela_feats = (const float*)d_in[6];
    const float* p_attr     = (const float*)d_in[7];
    const float* p_obj      = (const float*)d_in[8];
    const float* p_rela     = (const float*)d_in[9];
    const float* attr_masks = (const float*)d_in[10];
    const float* att_masks  = (const float*)d_in[11];
    const float* rela_masks = (const float*)d_in[12];
    const float* att_Wih    = (const float*)d_in[13];
    const float* att_Whh    = (const float*)d_in[14];
    const float* att_bih    = (const float*)d_in[15];
    const float* att_bhh    = (const float*)d_in[16];
    const float* lang_Wih   = (const float*)d_in[17];
    const float* lang_Whh   = (const float*)d_in[18];
    const float* lang_bih   = (const float*)d_in[19];
    const float* lang_bhh   = (const float*)d_in[20];
    const float* attr_Wq    = (const float*)d_in[21];
    const float* attr_bq    = (const float*)d_in[22];
    const float* attr_wa    = (const float*)d_in[23];
    const float* attr_ba    = (const float*)d_in[24];
    const float* obj_Wq     = (const float*)d_in[25];
    const float* obj_bq     = (const float*)d_in[26];
    const float* obj_wa     = (const float*)d_in[27];
    const float* obj_ba     = (const float*)d_in[28];
    const float* rela_Wq    = (const float*)d_in[29];
    const float* rela_bq    = (const float*)d_in[30];
    const float* rela_wa    = (const float*)d_in[31];
    const float* rela_ba    = (const float*)d_in[32];

    float* out = (float*)d_out;
    const float* h0 = state_h;            // state_h[0]
    const float* h1 = state_h + BR;       // state_h[1] (prev_h)
    float* h_att = out + BR;              // final h_att slot doubles as scratch

    // workspace: gate partials (f16), q partials (f16), attended feats (f32)
    _Float16* g16 = (_Float16*)d_ws;                       // [2][1024][4096]
    _Float16* q16 = g16 + 2ull * 1024 * 4096;              // [3][2][1024][512]
    float*    a32 = (float*)(q16 + 6ull * 1024 * 512);     // [3][1024][1024]
    float* a_attr = a32;
    float* a_obj  = a32 + BR;
    float* a_rela = a32 + 2 * BR;

    dim3 blk(256);

    // 1) att-LSTM gates: A = [h1 | fc | xt | h0], K=4096, split-K 2x2048
    gemm_hf<<<dim3(32, 8, 2), blk, 0, stream>>>(
        h1, fc, xt, h0, h0,
        att_Wih, 3072, 3072, att_Whh, 1024,
        g16, 4096, 2048);
    // 2) att-LSTM elementwise -> h_att (out[BR]), c_att (out[3BR])
    lstm2<<<dim3(4096), blk, 0, stream>>>(
        g16, g16 + 4ull * BR, att_bih, att_bhh, state_c,
        h_att, nullptr, out + 3 * BR);
    // 3) q = h_att @ Wq^T (bias added in attend), K=1024 split 2x512
    gemm_hf<<<dim3(4, 8, 2), blk, 0, stream>>>(
        h_att, h_att, h_att, h_att, h_att,
        attr_Wq, 1024, 1024, attr_Wq, 1024, q16, 512, 512);
    gemm_hf<<<dim3(4, 8, 2), blk, 0, stream>>>(
        h_att, h_att, h_att, h_att, h_att,
        obj_Wq, 1024, 1024, obj_Wq, 1024, q16 + 2ull * 512 * 1024, 512, 512);
    gemm_hf<<<dim3(4, 8, 2), blk, 0, stream>>>(
        h_att, h_att, h_att, h_att, h_att,
        rela_Wq, 1024, 1024, rela_Wq, 1024, q16 + 4ull * 512 * 1024, 512, 512);
    // 4) attends
    attend2<<<dim3(1024), blk, 0, stream>>>(
        attr_feats, p_attr, attr_masks,
        q16, q16 + 1ull * 512 * 1024, attr_bq, attr_wa, attr_ba, a_attr, 16);
    attend2<<<dim3(1024), blk, 0, stream>>>(
        obj_feats, p_obj, att_masks,
        q16 + 2ull * 512 * 1024, q16 + 3ull * 512 * 1024, obj_bq, obj_wa, obj_ba, a_obj, 36);
    attend2<<<dim3(1024), blk, 0, stream>>>(
        rela_feats, p_rela, rela_masks,
        q16 + 4ull * 512 * 1024, q16 + 5ull * 512 * 1024, rela_bq, rela_wa, rela_ba, a_rela, 64);
    // 5) lang-LSTM gates: A = [h_att | a_attr | a_obj | a_rela | h1], K=5120 split 2x2560
    gemm_hf<<<dim3(32, 8, 2), blk, 0, stream>>>(
        h_att, a_attr, a_obj, a_rela, h1,
        lang_Wih, 4096, 4096, lang_Whh, 1024,
        g16, 4096, 2560);
    // 6) lang-LSTM elementwise -> output (out[0]), h_lang (out[2BR]), c_lang (out[4BR])
    lstm2<<<dim3(4096), blk, 0, stream>>>(
        g16, g16 + 4ull * BR, lang_bih, lang_bhh, state_c + BR,
        out, out + 2 * BR, out + 4 * BR);
}